// Round 1
// 141.196 us; speedup vs baseline: 1.1067x; 1.1067x over previous
//
#include <hip/hip_runtime.h>
#include <math.h>

#define EPS 1e-8f
#define KT 32
#define HB 256       // histogram / scatter blocks (must equal blockDim)

// ---------------------------------------------------------------------------
// K0: blocks [0,S): rinv[s] = 1/(||S_s||+eps)
//     blocks [S,S+B): Hs[b,:] = H[b,:]/(||H_b||+eps), gscale[b]=0.005*||G_b||
//     blocks [S+B, S+B+HB): per-block disease histogram of edges (P1)
// ---------------------------------------------------------------------------
__global__ void k_norms_hist(const float* __restrict__ Sg, const float* __restrict__ Hg,
                             const float* __restrict__ Gg, const int* __restrict__ ed,
                             float* __restrict__ rinv, float* __restrict__ Hs,
                             float* __restrict__ gscale, int* __restrict__ hist,
                             int Srows, int Fdim, int Bdim, int Dd, int E) {
    __shared__ float wsum[4];
    __shared__ float wsum2[4];
    __shared__ float bc0;
    __shared__ int cnt[1024];
    int row = blockIdx.x;
    int tid = threadIdx.x;
    int lane = tid & 63, wv = tid >> 6;

    if (row < Srows) {
        const float* p = Sg + (size_t)row * Fdim;
        float acc = 0.f;
        for (int i = tid; i < Fdim; i += 256) { float v = p[i]; acc += v * v; }
        for (int off = 32; off > 0; off >>= 1) acc += __shfl_down(acc, off, 64);
        if (lane == 0) wsum[wv] = acc;
        __syncthreads();
        if (tid == 0) {
            float t = wsum[0] + wsum[1] + wsum[2] + wsum[3];
            rinv[row] = 1.0f / (sqrtf(t) + EPS);
        }
    } else if (row < Srows + Bdim) {
        int b = row - Srows;
        const float* ph = Hg + (size_t)b * Fdim;
        const float* pg = Gg + (size_t)b * Fdim;
        float ah = 0.f, ag = 0.f;
        for (int i = tid; i < Fdim; i += 256) {
            float h = ph[i]; ah += h * h;
            float g = pg[i]; ag += g * g;
        }
        for (int off = 32; off > 0; off >>= 1) {
            ah += __shfl_down(ah, off, 64);
            ag += __shfl_down(ag, off, 64);
        }
        if (lane == 0) { wsum[wv] = ah; wsum2[wv] = ag; }
        __syncthreads();
        if (tid == 0) {
            float th = wsum[0] + wsum[1] + wsum[2] + wsum[3];
            float tg = wsum2[0] + wsum2[1] + wsum2[2] + wsum2[3];
            bc0 = 1.0f / (sqrtf(th) + EPS);
            gscale[b] = 0.005f * sqrtf(tg);   // 0.01 (eta) * 0.5 (sim rescale)
        }
        __syncthreads();
        float hn = bc0;
        float* dst = Hs + (size_t)b * Fdim;
        for (int i = tid; i < Fdim; i += 256) dst[i] = ph[i] * hn;
    } else {
        int h = row - Srows - Bdim;
        for (int i = tid; i < Dd; i += 256) cnt[i] = 0;
        __syncthreads();
        int chunk = (E + HB - 1) / HB;
        int e0 = h * chunk;
        int e1 = min(E, e0 + chunk);
        for (int e = e0 + tid; e < e1; e += 256) atomicAdd(&cnt[ed[e]], 1);
        __syncthreads();
        for (int d = tid; d < Dd; d += 256) hist[(size_t)d * HB + h] = cnt[d];
    }
}

// ---------------------------------------------------------------------------
// K1: blocks [0,ng1): GEMM1  Pt[s][b] = rinv[s] * sum_k Hs[b,k]*Sg[s,k]
//       (32 s-rows x 64 b per block, full K, s-major float4 stores)
//     blocks [ng1, ng1+D): P2 per-d exclusive scan of hist over blocks ->
//       offs[d][h], total[d]
// ---------------------------------------------------------------------------
__global__ __launch_bounds__(256) void k_g1scan(
        const float* __restrict__ Hs, const float* __restrict__ Sg,
        const float* __restrict__ rinv, float* __restrict__ Pt,
        const int* __restrict__ hist, int* __restrict__ offs,
        int* __restrict__ total, int Srows, int Fdim, int ng1) {
    __shared__ float smem[KT * 104];
    __shared__ int iws[4];
    #define LA(k, i) smem[(k) * 68 + (i)]
    #define LB(k, i) smem[KT * 68 + (k) * 36 + (i)]
    int id = blockIdx.x;
    int tid = threadIdx.x;

    if (id < ng1) {
        int tx = tid & 15;          // b: 4 each
        int ty = tid >> 4;          // s: 2 each
        int s0 = id * 32;

        float4 acc0 = {0.f, 0.f, 0.f, 0.f};
        float4 acc1 = {0.f, 0.f, 0.f, 0.f};

        for (int kt = 0; kt < Fdim; kt += KT) {
            #pragma unroll
            for (int i = 0; i < 8; i++) {
                int idx = tid + i * 256;
                int c = idx & 31, r = idx >> 5;
                LA(c, r) = Hs[(size_t)r * Fdim + kt + c];
            }
            #pragma unroll
            for (int i = 0; i < 4; i++) {
                int idx = tid + i * 256;
                int c = idx & 31, r = idx >> 5;
                LB(c, r) = Sg[(size_t)(s0 + r) * Fdim + kt + c];
            }
            __syncthreads();
            #pragma unroll
            for (int k = 0; k < KT; k++) {
                float4 hv = *(const float4*)&LA(k, tx * 4);
                float2 sv = *(const float2*)&LB(k, ty * 2);
                acc0.x += sv.x * hv.x; acc0.y += sv.x * hv.y;
                acc0.z += sv.x * hv.z; acc0.w += sv.x * hv.w;
                acc1.x += sv.y * hv.x; acc1.y += sv.y * hv.y;
                acc1.z += sv.y * hv.z; acc1.w += sv.y * hv.w;
            }
            __syncthreads();
        }
        int sa = s0 + ty * 2;
        float r0 = rinv[sa], r1 = rinv[sa + 1];
        float4 o0, o1;
        o0.x = acc0.x * r0; o0.y = acc0.y * r0; o0.z = acc0.z * r0; o0.w = acc0.w * r0;
        o1.x = acc1.x * r1; o1.y = acc1.y * r1; o1.z = acc1.z * r1; o1.w = acc1.w * r1;
        *(float4*)&Pt[(size_t)sa * 64 + tx * 4]       = o0;
        *(float4*)&Pt[(size_t)(sa + 1) * 64 + tx * 4] = o1;
    } else {
        int d = id - ng1;
        int lane = tid & 63, w = tid >> 6;
        int v = hist[(size_t)d * HB + tid];
        int x = v;
        #pragma unroll
        for (int off = 1; off < 64; off <<= 1) {
            int n = __shfl_up(x, off, 64);
            if (lane >= off) x += n;
        }
        if (lane == 63) iws[w] = x;
        __syncthreads();
        int add = 0;
        for (int j = 0; j < w; j++) add += iws[j];
        offs[(size_t)d * HB + tid] = add + x - v;     // exclusive over blocks
        if (tid == 255) total[d] = add + x;
    }
    #undef LA
    #undef LB
}

// ---------------------------------------------------------------------------
// exclusive scan of total[0..1023] into LDS sbase (256 threads, 4 each)
// ---------------------------------------------------------------------------
__device__ __forceinline__ void scan_base_1024(const int* __restrict__ total, int tid,
                                               int* sbase, int* iws) {
    int4 t = ((const int4*)total)[tid];
    int s = t.x + t.y + t.z + t.w;
    int lane = tid & 63, w = tid >> 6;
    int x = s;
    #pragma unroll
    for (int off = 1; off < 64; off <<= 1) {
        int n = __shfl_up(x, off, 64);
        if (lane >= off) x += n;
    }
    if (lane == 63) iws[w] = x;
    __syncthreads();
    int add = 0;
    for (int j = 0; j < w; j++) add += iws[j];
    int e = add + x - s;
    ((int4*)sbase)[tid] = make_int4(e, e + t.x, e + t.x + t.y, e + t.x + t.y + t.z);
}

// ---------------------------------------------------------------------------
// K2: blocks [0,HB): P4 scatter — counting-sort edges by disease into
//       sorted[] as (es, ew) pairs. Zero global atomics (LDS counters only).
//     block HB: publish base[d] (exclusive scan of total) for K3.
// ---------------------------------------------------------------------------
__global__ __launch_bounds__(256) void k_scatter(
        const int* __restrict__ ed, const int* __restrict__ es,
        const float* __restrict__ ew, const int* __restrict__ offs,
        const int* __restrict__ total, int* __restrict__ base,
        int2* __restrict__ sorted, int E, int Dd) {
    __shared__ int sbase[1024];
    __shared__ int scnt[1024];
    __shared__ int iws[4];
    int h = blockIdx.x;
    int tid = threadIdx.x;

    scan_base_1024(total, tid, sbase, iws);
    __syncthreads();

    if (h == HB) {                       // publisher block
        for (int d = tid; d < Dd; d += 256) base[d] = sbase[d];
        return;
    }

    for (int d = tid; d < Dd; d += 256) {
        sbase[d] += offs[(size_t)d * HB + h];   // start[d] for this block
        scnt[d] = 0;
    }
    __syncthreads();

    int chunk = (E + HB - 1) / HB;
    int e0 = h * chunk;
    int e1 = min(E, e0 + chunk);
    for (int e = e0 + tid; e < e1; e += 256) {
        int d = ed[e];
        int r = atomicAdd(&scnt[d], 1);
        sorted[sbase[d] + r] = make_int2(es[e], __float_as_int(ew[e]));
    }
}

// ---------------------------------------------------------------------------
// K3: gather — block d: out[b,d] = gscale[b]*(sum_e ew*Pt[es][b] + sum_e ew)
//     4 waves split the bucket; lane = b; Pt columns are 256B coalesced
//     L2-resident reads. Register accumulation, LDS combine, direct out write.
// ---------------------------------------------------------------------------
__global__ __launch_bounds__(256) void k_gather(
        const int2* __restrict__ sorted, const float* __restrict__ Pt,
        const int* __restrict__ base, const int* __restrict__ total,
        const float* __restrict__ gscale, float* __restrict__ out, int Dd) {
    __shared__ float sacc[4][64];
    __shared__ float scs[4];
    int d = blockIdx.x;
    int tid = threadIdx.x;
    int lane = tid & 63, w = tid >> 6;
    int b0 = base[d];
    int cnt = total[d];
    const int2* sp = sorted + b0;
    float acc = 0.f, cs = 0.f;
    #pragma unroll 8
    for (int i = w; i < cnt; i += 4) {
        int2 p = sp[i];
        float wt = __int_as_float(p.y);
        acc += wt * Pt[(size_t)p.x * 64 + lane];
        cs += wt;
    }
    sacc[w][lane] = acc;
    if (lane == 0) scs[w] = cs;
    __syncthreads();
    if (tid < 64) {
        float a = sacc[0][tid] + sacc[1][tid] + sacc[2][tid] + sacc[3][tid]
                + scs[0] + scs[1] + scs[2] + scs[3];
        out[(size_t)tid * Dd + d] = gscale[tid] * a;
    }
}

extern "C" void kernel_launch(void* const* d_in, const int* in_sizes, int n_in,
                              void* d_out, int out_size, void* d_ws, size_t ws_size,
                              hipStream_t stream) {
    const float* H  = (const float*)d_in[0];
    const float* G  = (const float*)d_in[1];
    const float* Sg = (const float*)d_in[2];
    const float* ew = (const float*)d_in[3];
    const int*   ed = (const int*)d_in[4];
    const int*   es = (const int*)d_in[5];

    const int B = 64;
    const int F = in_sizes[0] / B;        // 512
    const int S = in_sizes[2] / F;        // 8192
    const int E = in_sizes[3];            // 500000
    const int D = out_size / B;           // 1024
    const int ng1 = S / 32;               // 256
    float* out = (float*)d_out;

    // workspace layout (float units; every buffer fully written before read)
    float* ws = (float*)d_ws;
    size_t off = 0;
    float* rinv   = ws + off; off += (size_t)S;            // 8192
    float* Hs     = ws + off; off += (size_t)B * F;        // 32768
    float* gscale = ws + off; off += 256;
    float* Pt     = ws + off; off += (size_t)S * B;        // 524288 (2 MB)
    int*   hist   = (int*)(ws + off); off += (size_t)D * HB;   // 1 MB
    int*   offs   = (int*)(ws + off); off += (size_t)D * HB;   // 1 MB
    int*   total  = (int*)(ws + off); off += (size_t)D;
    int*   base   = (int*)(ws + off); off += (size_t)D;
    int2*  sorted = (int2*)(ws + off); off += 2 * (size_t)E;   // 4 MB

    // K0: norms + edge histogram (independent block families)
    k_norms_hist<<<S + B + HB, 256, 0, stream>>>(Sg, H, G, ed, rinv, Hs, gscale,
                                                 hist, S, F, B, D, E);
    // K1: GEMM1 (ng1 blocks) || per-d offset scan (D blocks)
    k_g1scan<<<ng1 + D, 256, 0, stream>>>(Hs, Sg, rinv, Pt, hist, offs, total,
                                          S, F, ng1);
    // K2: counting-sort scatter (HB blocks) + base publisher (1 block)
    k_scatter<<<HB + 1, 256, 0, stream>>>(ed, es, ew, offs, total, base,
                                          sorted, E, D);
    // K3: per-disease register gather -> out
    k_gather<<<D, 256, 0, stream>>>(sorted, Pt, base, total, gscale, out, D);
}